// Round 7
// baseline (169.610 us; speedup 1.0000x reference)
//
#include <hip/hip_runtime.h>

// Problem constants (fixed by the reference)
#define BB 1024
#define LL 256
#define DD 64
#define TDIM 100
#define NNODES 20000

typedef _Float16 half8_t __attribute__((ext_vector_type(8)));
typedef float f32x4 __attribute__((ext_vector_type(4)));

// One block = one batch row, BOTH sides. 512 threads (8 waves):
// thread t -> side = t>>8 (wave-uniform), pos = t&255.
// vs R6 (one block per (row,side), 168.5us): histogram/w2/coeff staging done
// ONCE per row instead of twice, and 16 waves/CU (2 blocks x 8 waves) instead
// of 8 -- doubled latency hiding for the barrier-dense hist phase.
// MFMA work per wave unchanged: wave w owns 64 of the 512 G-rows.
__global__ __launch_bounds__(512, 4) void tni_kernel(
    const int* __restrict__ src_ids, const int* __restrict__ dst_ids,
    const float* __restrict__ src_tm, const float* __restrict__ dst_tm,
    const float* __restrict__ node_tm,
    const float* __restrict__ w_time, const float* __restrict__ b_time,
    const float* __restrict__ w_ts, const float* __restrict__ b_ts,
    const float* __restrict__ w1, const float* __restrict__ b1,
    const float* __restrict__ w2, const float* __restrict__ b2,
    float* __restrict__ out)
{
    // 73,728B union: [hist: 10000 u32 (40KB)] | [W2v 8KB + Gv(512 rows) 64KB]
    __shared__ unsigned int uS[18432];
    __shared__ float wrv[TDIM], brv[TDIM], wtsv[TDIM]; // coeffs (revolutions)
    __shared__ float w1v[DD], b1v[DD];

    unsigned int* hist = uS;
    half8_t* W2v = (half8_t*)uS;             // [DD*8], valid after hist phase
    half8_t* Gv  = (half8_t*)(uS + 2048);    // [512*8]

    const int t    = threadIdx.x;
    const int side = t >> 8;                 // wave-uniform (waves 0-3 / 4-7)
    const int pos  = t & 255;
    const int b    = blockIdx.x;

    // ---- per-thread inputs (coalesced; side-uniform per wave) ----
    const int   my_id = side ? dst_ids[b*LL + pos] : src_ids[b*LL + pos];
    const float my_tm = side ? dst_tm [b*LL + pos] : src_tm [b*LL + pos];

    // prefetch w2 into 8 regs; LDS write deferred until hist region frees
    float w2r[8];
    #pragma unroll
    for (int i = 0; i < 8; ++i) w2r[i] = w2[t + 512*i];

    if (t < TDIM) {
        const float inv2pi = 0.15915494309189535f;   // v_cos_f32 takes revolutions
        wrv[t]  = w_time[t] * inv2pi;
        brv[t]  = b_time[t] * inv2pi;
        wtsv[t] = w_ts[t];
    }
    else if (t >= 128 && t < 128 + DD) {
        w1v[t-128] = w1[t-128];
        b1v[t-128] = b1[t-128];
    }

    // ---- counts via one shared packed-u16 histogram, touched-word clears ----
    // epoch A: side-0 threads add the src row; everyone reads my_id's slot -> c1
    // epoch B: side-1 threads add the dst row; everyone reads my_id's slot -> c2
    const int myw  = my_id >> 1;
    const int mysh = (my_id & 1) * 16;

    hist[myw] = 0;                          // covers all read & write words
    __syncthreads();
    if (!side && my_id) atomicAdd(&hist[myw], 1u << mysh);
    __syncthreads();
    unsigned c1 = (hist[myw] >> mysh) & 0xffffu;   // count in src row
    __syncthreads();
    hist[myw] = 0;
    __syncthreads();
    if (side && my_id) atomicAdd(&hist[myw], 1u << mysh);
    __syncthreads();
    unsigned c2 = (hist[myw] >> mysh) & 0xffffu;   // count in dst row
    if (my_id == 0) { c1 = 0; c2 = 0; }   // padding id -> zero count (mask)
    __syncthreads();                       // hist reads done; region reusable

    // ---- time weight: sigmoid(cos(td*w+b) @ w_ts + b_ts) ----
    float td = node_tm[b] - my_tm;
    float z  = b_ts[0];
    #pragma unroll 4
    for (int k = 0; k < TDIM; ++k) {
        float r = __builtin_amdgcn_fractf(fmaf(td, wrv[k], brv[k]));
        z = fmaf(__builtin_amdgcn_cosf(r), wtsv[k], z);
    }
    float ee  = __builtin_amdgcn_exp2f(-1.44269504f * z);  // exp(-z)
    float wgt = __builtin_amdgcn_rcpf(1.0f + ee);          // sigmoid(z)
    float c1w = (float)c1 * wgt;
    float c2w = (float)c2 * wgt;

    // ---- stage w2 (from regs) -> W2v = w2^T rows [d][e] fp16, swizzled ----
    {
        _Float16* w2s = (_Float16*)W2v;
        #pragma unroll
        for (int i = 0; i < 8; ++i) {
            int idx = t + 512*i;            // 0..4095
            int e = idx >> 6, d = idx & 63;
            int chunk = (e >> 3) ^ (d & 7); // XOR swizzle on 16B chunks within a row
            w2s[d*64 + (chunk << 3) + (e & 7)] = (_Float16)w2r[i];
        }
    }

    // ---- g[e] = relu(c1w*w1+b1) + relu(c2w*w1+b1), fp16, A-fragment row t ----
    #pragma unroll
    for (int c = 0; c < 8; ++c) {
        half8_t h;
        #pragma unroll
        for (int j = 0; j < 8; ++j) {
            float w1e = w1v[c*8 + j], b1e = b1v[c*8 + j];
            float g = fmaxf(fmaf(c1w, w1e, b1e), 0.f)
                    + fmaxf(fmaf(c2w, w1e, b1e), 0.f);
            h[j] = (_Float16)g;
        }
        Gv[t*8 + (c ^ (t & 7))] = h;      // G row t (q = side*256+pos = t)
    }
    __syncthreads();

    // ---- MFMA: [512 x 64] x [64 x 64], wave w owns rows 64w..64w+63 ----
    const int w    = t >> 6;
    const int l    = t & 63;
    const int quad = l >> 4;
    const int lr   = l & 15;

    f32x4 acc[4][4];
    #pragma unroll
    for (int mt = 0; mt < 4; ++mt)
        #pragma unroll
        for (int nt = 0; nt < 4; ++nt) {
            f32x4 zz = {0.f, 0.f, 0.f, 0.f};
            acc[mt][nt] = zz;
        }

    #pragma unroll
    for (int s = 0; s < 2; ++s) {         // K steps of 32
        const int c = s*4 + quad;         // logical 16B chunk (8 k's) this lane reads
        half8_t bfr[4], afr[4];
        #pragma unroll
        for (int nt = 0; nt < 4; ++nt) {  // B: lane holds B[k=quad*8+j][n=lane&15]
            int n = nt*16 + lr;
            bfr[nt] = W2v[n*8 + (c ^ (n & 7))];
        }
        #pragma unroll
        for (int mt = 0; mt < 4; ++mt) {  // A: lane holds A[m=lane&15][k=quad*8+j]
            int row = w*64 + mt*16 + lr;
            afr[mt] = Gv[row*8 + (c ^ (row & 7))];
        }
        #pragma unroll
        for (int mt = 0; mt < 4; ++mt)
            #pragma unroll
            for (int nt = 0; nt < 4; ++nt)
                acc[mt][nt] = __builtin_amdgcn_mfma_f32_16x16x32_f16(
                    afr[mt], bfr[nt], acc[mt][nt], 0, 0, 0);
    }

    // ---- epilogue: +2*b2, store fp32. C layout: col=lane&15, row=quad*4+reg ----
    float b2v[4];
    #pragma unroll
    for (int nt = 0; nt < 4; ++nt)
        b2v[nt] = 2.f * b2[nt*16 + lr];

    const size_t halfo = (size_t)BB * LL * DD;
    #pragma unroll
    for (int mt = 0; mt < 4; ++mt) {
        #pragma unroll
        for (int r = 0; r < 4; ++r) {
            int q = w*64 + mt*16 + quad*4 + r;       // 0..511
            int qs = q >> 8, qp = q & 255;           // side, position
            #pragma unroll
            for (int nt = 0; nt < 4; ++nt) {
                out[(size_t)qs*halfo + (size_t)b*(LL*DD) + qp*DD + nt*16 + lr] =
                    acc[mt][nt][r] + b2v[nt];
            }
        }
    }
}

extern "C" void kernel_launch(void* const* d_in, const int* in_sizes, int n_in,
                              void* d_out, int out_size, void* d_ws, size_t ws_size,
                              hipStream_t stream) {
    const int* src_ids = (const int*)d_in[0];
    const int* dst_ids = (const int*)d_in[1];
    const float* src_tm  = (const float*)d_in[2];
    const float* dst_tm  = (const float*)d_in[3];
    const float* node_tm = (const float*)d_in[4];
    // d_in[5] = num_nodes (fixed 20000; counts via LDS histogram)
    const float* w_time = (const float*)d_in[6];
    const float* b_time = (const float*)d_in[7];
    const float* w_ts   = (const float*)d_in[8];
    const float* b_ts   = (const float*)d_in[9];
    const float* w1     = (const float*)d_in[10];
    const float* b1     = (const float*)d_in[11];
    const float* w2     = (const float*)d_in[12];
    const float* b2     = (const float*)d_in[13];
    float* out = (float*)d_out;

    tni_kernel<<<dim3(BB), dim3(512), 0, stream>>>(
        src_ids, dst_ids, src_tm, dst_tm, node_tm,
        w_time, b_time, w_ts, b_ts, w1, b1, w2, b2, out);
}